// Round 5
// baseline (653.430 us; speedup 1.0000x reference)
//
#include <hip/hip_runtime.h>

// B=1024, H=56, J=64, N=56, I=64.
// t4[b,i,m,n] = sum_{k,j} x[b, m+k-1, j, n] * W2[i,k,j]   (zero-padded in h)
// y[b,i,m,(n+1)%56] = t4[b,i,m,n]*W1[i,0] + t4[b,i,(m-1)%56,n]*W1[i,1]
//
// Restructure: fold the W1 mix into the conv weights ->
//   y[m] = sum_{k'=0..3} W2'[i,k',j] * xp[m-2+k', j, n]   (m = 1..55, zero-pad)
//   W2'  = [b*W0, a*W0+b*W1, a*W1+b*W2, a*W2]  (a=W1[:,0], b=W1[:,1])
//   y[0] = sum over taps (x54, x55, x0, x1) with W2'' = [b*W0, b*W1, a*W1, a*W2]
// Both weight sets precomputed (bf16) in d_ws by prep_weights.
// n-roll via row rotation: LDS row r holds source col n = 28q-1+r.
// 2048 blocks (batch x n-half) for occupancy; 5-slot LDS ring, unroll 5.

#define HH 56
#define ROWE 328   // ushort row stride: 5 slots * 64 + 8 pad (164 dw = 4 mod 32)
#define SLOTE 64

typedef __attribute__((ext_vector_type(8))) short short8_t;
typedef __attribute__((ext_vector_type(4))) short short4_t;
typedef __attribute__((ext_vector_type(4))) float f32x4;

__device__ __forceinline__ unsigned short f2bf(float f) {
  union { float f; unsigned u; } v; v.f = f;
  return (unsigned short)((v.u + 0x7FFFu + ((v.u >> 16) & 1u)) >> 16);
}

#define BARRIER() do {                                   \
    asm volatile("s_waitcnt lgkmcnt(0)" ::: "memory");   \
    __builtin_amdgcn_s_barrier();                        \
    __builtin_amdgcn_sched_barrier(0);                   \
  } while (0)

// ---- pre-kernel: merged 4-tap weight sets (bf16) into ws ----
__global__ void prep_weights(const float* __restrict__ W1,
                             const float* __restrict__ W2,
                             unsigned short* __restrict__ wp) {
  const int t = threadIdx.x;            // 256 threads
  const int i = t >> 2;
  const int j0 = (t & 3) * 16;
  const float a = W1[i * 2 + 0], b = W1[i * 2 + 1];
  const float* w = W2 + i * 192;
  unsigned short* p0 = wp + i * 256;            // W2'  (m = 1..55)
  unsigned short* p1 = wp + 16384 + i * 256;    // W2'' (m = 0 wrap)
  for (int j = j0; j < j0 + 16; ++j) {
    const float w0 = w[j], w1 = w[64 + j], w2 = w[128 + j];
    p0[j]       = f2bf(b * w0);
    p0[64 + j]  = f2bf(a * w0 + b * w1);
    p0[128 + j] = f2bf(a * w1 + b * w2);
    p0[192 + j] = f2bf(a * w2);
    p1[j]       = f2bf(b * w0);
    p1[64 + j]  = f2bf(b * w1);
    p1[128 + j] = f2bf(a * w1);
    p1[192 + j] = f2bf(a * w2);
  }
}

__global__ __launch_bounds__(256, 6) void conv4tap(
    const float* __restrict__ x, const unsigned short* __restrict__ wp,
    float* __restrict__ out) {
  __shared__ unsigned short lds[32 * ROWE];   // 20992 B

  const int tid  = threadIdx.x;
  const int wave = tid >> 6;
  const int lane = tid & 63;
  const int lq   = lane & 15;
  const int lg   = lane >> 4;

  const int bid = blockIdx.x;
  const int q = bid & 1;           // n-half: output cols [28q, 28q+28)
  const int b = bid >> 1;          // batch
  const float* __restrict__ xb = x + (size_t)b * (HH * 64 * 56);

  // ---- A fragments: W2' (bf16, from ws), 64 x 256 ----
  short8_t afrag[8];
  {
    const unsigned short* ap = wp + (16 * wave + lq) * 256 + lg * 8;
    #pragma unroll
    for (int s = 0; s < 8; ++s) afrag[s] = *(const short8_t*)(ap + s * 32);
  }

  // ---- B-row bases: col tile t reads LDS row 16t+lq (row r = source col) ----
  const int rb0 = lq * ROWE + lg * 8;
  const int rb1 = rb0 + 16 * ROWE;

  // ---- output base: i = 16*wave + 4*lg + r, col = 28q + 16t + lq ----
  float* const outp = out + ((size_t)b * 64 + 16 * wave + 4 * lg) * (HH * 56)
                      + 28 * q + lq;

  // ---- staging: 128 workers = 8 n-quads x 16 j-quads ----
  // rows: nq==0 is the wrap quad (only e=3 -> row 0); else rows 4nq-3+e.
  const bool stg = tid < 128;
  const int nq = (tid >> 4) & 7;
  const int jq = tid & 15;
  const int nbase = (nq == 0) ? ((28 * q + 52) % 56) : (28 * q + 4 * (nq - 1));
  const float* const xsrc = xb + (size_t)(jq * 4) * 56 + nbase;

  auto issue = [&](int h, float4* R) {
    if (stg && h <= HH) {
      if (h >= 0 && h < HH) {
        const float* p = xsrc + (size_t)h * (64 * 56);
        R[0] = *(const float4*)(p);
        R[1] = *(const float4*)(p + 56);
        R[2] = *(const float4*)(p + 112);
        R[3] = *(const float4*)(p + 168);
      } else {
        float4 z = {0.f, 0.f, 0.f, 0.f};
        R[0] = z; R[1] = z; R[2] = z; R[3] = z;
      }
    }
  };

  auto putS = [&](int h, int slot, const float4* R) {
    if (stg && h <= HH) {
      if (nq == 0) {                 // wrap quad: only n = nbase+3 -> row 0
        short4_t v;
        v[0] = (short)f2bf(R[0].w); v[1] = (short)f2bf(R[1].w);
        v[2] = (short)f2bf(R[2].w); v[3] = (short)f2bf(R[3].w);
        *(short4_t*)&lds[slot * SLOTE + jq * 4] = v;
      } else {
        short4_t v0, v1, v2, v3;
        v0[0] = (short)f2bf(R[0].x); v0[1] = (short)f2bf(R[1].x); v0[2] = (short)f2bf(R[2].x); v0[3] = (short)f2bf(R[3].x);
        v1[0] = (short)f2bf(R[0].y); v1[1] = (short)f2bf(R[1].y); v1[2] = (short)f2bf(R[2].y); v1[3] = (short)f2bf(R[3].y);
        v2[0] = (short)f2bf(R[0].z); v2[1] = (short)f2bf(R[1].z); v2[2] = (short)f2bf(R[2].z); v2[3] = (short)f2bf(R[3].z);
        v3[0] = (short)f2bf(R[0].w); v3[1] = (short)f2bf(R[1].w); v3[2] = (short)f2bf(R[2].w); v3[3] = (short)f2bf(R[3].w);
        unsigned short* base = &lds[(4 * nq - 3) * ROWE + slot * SLOTE + jq * 4];
        *(short4_t*)(base)            = v0;
        *(short4_t*)(base + ROWE)     = v1;
        *(short4_t*)(base + 2 * ROWE) = v2;
        *(short4_t*)(base + 3 * ROWE) = v3;
      }
    }
  };

  auto compute = [&](f32x4* acc, int s0, int s1, int s2, int s3) {
    acc[0] = (f32x4){0.f, 0.f, 0.f, 0.f};
    acc[1] = (f32x4){0.f, 0.f, 0.f, 0.f};
    const int so[4] = {s0, s1, s2, s3};
    #pragma unroll
    for (int k = 0; k < 4; ++k) {
      #pragma unroll
      for (int half = 0; half < 2; ++half) {
        const int off = so[k] * SLOTE + half * 32;
        const short8_t b0 = *(const short8_t*)&lds[rb0 + off];
        const short8_t b1 = *(const short8_t*)&lds[rb1 + off];
        acc[0] = __builtin_amdgcn_mfma_f32_16x16x32_bf16(afrag[2 * k + half], b0, acc[0], 0, 0, 0);
        acc[1] = __builtin_amdgcn_mfma_f32_16x16x32_bf16(afrag[2 * k + half], b1, acc[1], 0, 0, 0);
      }
    }
  };

  auto storeY = [&](int m, const f32x4* acc) {
    float* pm = outp + m * 56;
    #pragma unroll
    for (int r = 0; r < 4; ++r) {
      pm[(size_t)r * 3136] = acc[0][r];
      if (lq < 12) pm[(size_t)r * 3136 + 16] = acc[1][r];
    }
  };

  // ---- prologue: zero pad rows 29..31 (read by discarded cols), stage h=-1..2 ----
  if (tid < 246) {
    const int row = 29 + tid / 82, c4 = (tid % 82) * 4;
    *(short4_t*)&lds[row * ROWE + c4] = (short4_t){0, 0, 0, 0};
  }
  float4 R[4];
  issue(-1, R); putS(-1, 4, R);
  issue(0, R);  putS(0, 0, R);
  issue(1, R);  putS(1, 1, R);
  issue(2, R);  putS(2, 2, R);
  BARRIER();
  issue(3, R);

  f32x4 acc[2];

  // ---- main loop: m = 1..50 (10 iters x 5 substeps, slots compile-time) ----
  #pragma unroll 1
  for (int u = 0; u < 10; ++u) {
    const int m0 = u * 5;
    compute(acc, 4, 0, 1, 2); putS(m0 + 3, 3, R); issue(m0 + 4, R); BARRIER(); storeY(m0 + 1, acc);
    compute(acc, 0, 1, 2, 3); putS(m0 + 4, 4, R); issue(m0 + 5, R); BARRIER(); storeY(m0 + 2, acc);
    compute(acc, 1, 2, 3, 4); putS(m0 + 5, 0, R); issue(m0 + 6, R); BARRIER(); storeY(m0 + 3, acc);
    compute(acc, 2, 3, 4, 0); putS(m0 + 6, 1, R); issue(m0 + 7, R); BARRIER(); storeY(m0 + 4, acc);
    compute(acc, 3, 4, 0, 1); putS(m0 + 7, 2, R); issue(m0 + 8, R); BARRIER(); storeY(m0 + 5, acc);
  }

  // ---- peeled m = 51..55, then the m=0 wrap substep with W2'' ----
  compute(acc, 4, 0, 1, 2); putS(53, 3, R); issue(54, R); BARRIER(); storeY(51, acc);
  compute(acc, 0, 1, 2, 3); putS(54, 4, R); issue(55, R); BARRIER(); storeY(52, acc);
  compute(acc, 1, 2, 3, 4); putS(55, 0, R); issue(56, R); BARRIER(); storeY(53, acc); // R <- zeros
  compute(acc, 2, 3, 4, 0); putS(56, 1, R); issue(0, R);  BARRIER(); storeY(54, acc);
  compute(acc, 3, 4, 0, 1); putS(0, 2, R);  issue(1, R);
  {
    const unsigned short* ap2 = wp + 16384 + (16 * wave + lq) * 256 + lg * 8;
    #pragma unroll
    for (int s = 0; s < 8; ++s) afrag[s] = *(const short8_t*)(ap2 + s * 32);
  }
  BARRIER(); storeY(55, acc);
  putS(1, 3, R);            // slot 3 free: m=55 reads finished at the barrier
  BARRIER();
  compute(acc, 4, 0, 2, 3); // taps: x54(s4), x55(s0), x0(s2), x1(s3) with W2''
  storeY(0, acc);
}

extern "C" void kernel_launch(void* const* d_in, const int* in_sizes, int n_in,
                              void* d_out, int out_size, void* d_ws, size_t ws_size,
                              hipStream_t stream) {
  const float* x  = (const float*)d_in[0];
  const float* W1 = (const float*)d_in[1];
  const float* W2 = (const float*)d_in[2];
  float* out = (float*)d_out;
  unsigned short* wp = (unsigned short*)d_ws;
  prep_weights<<<1, 256, 0, stream>>>(W1, W2, wp);
  conv4tap<<<2048, 256, 0, stream>>>(x, wp, out);
}

// Round 6
// 457.987 us; speedup vs baseline: 1.4267x; 1.4267x over previous
//
#include <hip/hip_runtime.h>

// B=1024, H=56, J=64, N=56, I=64.
// t4[b,i,m,n] = sum_{k,j} x[b, m+k-1, j, n] * W2[i,k,j]   (zero-padded in h)
// y[b,i,m,(n+1)%56] = t4[b,i,m,n]*W1[i,0] + t4[b,i,(m-1)%56,n]*W1[i,1]
//
// Folded: y[i,m,c] = sum_{k'=0..3} W2'[i,k',j] * x[m-2+k', j, (c-1)%56]
//   W2'  = [bW0, aW0+bW1, aW1+bW2, aW2]   (valid m=1..55, zero-padded)
//   m=0 (circular wrap) uses W2'' = [bW0, bW1, aW1, aW2] over x54,x55,x0,x1.
// n-roll folded into B-reads: col c reads LDS row (c+55)%56.
// 512 threads = 8 waves (4 i-groups x 2 n-halves); shared 5-slot LDS ring;
// lgkmcnt-only barriers (global loads stay in flight across phases).

#define HH 56
#define ROWE 328   // ushorts per n-row: 5 slots * 64 + 8 pad (656B rows)
#define SLOTE 64

typedef __attribute__((ext_vector_type(8))) short short8_t;
typedef __attribute__((ext_vector_type(4))) float f32x4;

__device__ __forceinline__ unsigned short f2bf(float f) {
  union { float f; unsigned u; } v; v.f = f;
  return (unsigned short)((v.u + 0x7FFFu + ((v.u >> 16) & 1u)) >> 16);
}

#define BARRIER() do {                                   \
    asm volatile("s_waitcnt lgkmcnt(0)" ::: "memory");   \
    __builtin_amdgcn_s_barrier();                        \
  } while (0)

// ---- pre-kernel: merged 4-tap weight sets (bf16) into ws ----
__global__ void prep_weights(const float* __restrict__ W1,
                             const float* __restrict__ W2,
                             unsigned short* __restrict__ wp) {
  const int t = threadIdx.x;            // 256 threads
  const int i = t >> 2;
  const int j0 = (t & 3) * 16;
  const float a = W1[i * 2 + 0], b = W1[i * 2 + 1];
  const float* w = W2 + i * 192;
  unsigned short* p0 = wp + i * 256;            // W2'  (m = 1..55)
  unsigned short* p1 = wp + 16384 + i * 256;    // W2'' (m = 0 wrap)
  for (int j = j0; j < j0 + 16; ++j) {
    const float w0 = w[j], w1 = w[64 + j], w2 = w[128 + j];
    p0[j]       = f2bf(b * w0);
    p0[64 + j]  = f2bf(a * w0 + b * w1);
    p0[128 + j] = f2bf(a * w1 + b * w2);
    p0[192 + j] = f2bf(a * w2);
    p1[j]       = f2bf(b * w0);
    p1[64 + j]  = f2bf(b * w1);
    p1[128 + j] = f2bf(a * w1);
    p1[192 + j] = f2bf(a * w2);
  }
}

__global__ __launch_bounds__(512, 6) void conv4tap(
    const float* __restrict__ x, const unsigned short* __restrict__ wp,
    float* __restrict__ out) {
  __shared__ unsigned short lds[56 * ROWE];   // 36736 B -> 4 blocks/CU by LDS

  const int tid  = threadIdx.x;
  const int wave = tid >> 6;          // 0..7
  const int iw   = wave >> 1;         // i-group: rows 16*iw..16*iw+15
  const int nh   = wave & 1;          // n-half: cols 28*nh..28*nh+27
  const int lane = tid & 63;
  const int lq   = lane & 15;
  const int lg   = lane >> 4;

  const int b = blockIdx.x;
  const float* __restrict__ xb = x + (size_t)b * (HH * 64 * 56);

  // ---- A fragments: W2' (64 x 256 bf16), i = 16*iw + lq ----
  short8_t afrag[8];
  {
    const unsigned short* ap = wp + ((16 * iw + lq) << 8) + lg * 8;
    #pragma unroll
    for (int s = 0; s < 8; ++s) afrag[s] = *(const short8_t*)(ap + s * 32);
  }

  // ---- B row bases: tile t, col c = 28*nh + 16t + lq -> row (c+55)%56 ----
  int rb[2];
  #pragma unroll
  for (int t = 0; t < 2; ++t)
    rb[t] = ((28 * nh + 16 * t + lq + 55) % 56) * ROWE + lg * 8;

  // ---- output base: i = 16*iw + 4*lg + r, col = 28*nh + 16t + lq ----
  float* const outp = out + ((size_t)b * 64 + 16 * iw + 4 * lg) * (HH * 56)
                      + 28 * nh + lq;

  // ---- staging: 448 active lanes = n-quad(14, from tid&15) x j-pair(32) ----
  const int nq = tid & 15;            // active < 14
  const int jq = tid >> 4;            // 0..31, j rows {2jq, 2jq+1}
  const bool stg = nq < 14;
  const float* const xsrc = xb + (size_t)(2 * jq) * 56 + 4 * nq;
  unsigned short* const sb = &lds[(size_t)(4 * nq) * ROWE + 2 * jq];

  auto issue = [&](int h, float4* R) {
    if (stg && h <= HH) {
      if (h >= 0 && h < HH) {
        const float* p = xsrc + (size_t)h * (64 * 56);
        R[0] = *(const float4*)(p);
        R[1] = *(const float4*)(p + 56);
      } else {
        float4 z = {0.f, 0.f, 0.f, 0.f};
        R[0] = z; R[1] = z;
      }
    }
  };

  // rows 4nq+e get cols {2jq, 2jq+1} as one packed dword write
  auto putS = [&](int h, int slot, const float4* R) {
    if (stg && h <= HH) {
      unsigned short* base = sb + slot * SLOTE;
      const unsigned q0 = (unsigned)f2bf(R[0].x) | ((unsigned)f2bf(R[1].x) << 16);
      const unsigned q1 = (unsigned)f2bf(R[0].y) | ((unsigned)f2bf(R[1].y) << 16);
      const unsigned q2 = (unsigned)f2bf(R[0].z) | ((unsigned)f2bf(R[1].z) << 16);
      const unsigned q3 = (unsigned)f2bf(R[0].w) | ((unsigned)f2bf(R[1].w) << 16);
      *(unsigned*)(base)            = q0;
      *(unsigned*)(base + ROWE)     = q1;
      *(unsigned*)(base + 2 * ROWE) = q2;
      *(unsigned*)(base + 3 * ROWE) = q3;
    }
  };

  auto compute = [&](f32x4* acc, int s0, int s1, int s2, int s3) {
    acc[0] = (f32x4){0.f, 0.f, 0.f, 0.f};
    acc[1] = (f32x4){0.f, 0.f, 0.f, 0.f};
    const int sl[4] = {s0, s1, s2, s3};
    #pragma unroll
    for (int s = 0; s < 8; ++s) {
      const int off = sl[s >> 1] * SLOTE + (s & 1) * 32;
      const short8_t b0 = *(const short8_t*)&lds[rb[0] + off];
      const short8_t b1 = *(const short8_t*)&lds[rb[1] + off];
      acc[0] = __builtin_amdgcn_mfma_f32_16x16x32_bf16(afrag[s], b0, acc[0], 0, 0, 0);
      acc[1] = __builtin_amdgcn_mfma_f32_16x16x32_bf16(afrag[s], b1, acc[1], 0, 0, 0);
    }
  };

  auto storeY = [&](int m, const f32x4* acc) {
    float* pm = outp + m * 56;
    #pragma unroll
    for (int r = 0; r < 4; ++r) {
      pm[(size_t)r * 3136] = acc[0][r];
      if (lq < 12) pm[(size_t)r * 3136 + 16] = acc[1][r];
    }
  };

  f32x4 acc[2];
  float4 R[2];

  // ---- prologue: stage slices -1,0,1,2 into slots 4,0,1,2 ----
  issue(-1, R); putS(-1, 4, R);
  issue(0, R);  putS(0, 0, R);
  issue(1, R);  putS(1, 1, R);
  issue(2, R);  putS(2, 2, R);
  BARRIER();
  issue(3, R);

  // ---- main: phases m=1..50, 10 iters x 5 substeps (slots static) ----
  // phase m: compute taps m-2..m+1; putS slice m+2; issue slice m+3.
  #pragma unroll 1
  for (int u = 0; u < 10; ++u) {
    const int m0 = 5 * u + 1;
    compute(acc, 4, 0, 1, 2); putS(m0 + 2, 3, R); issue(m0 + 3, R); BARRIER(); storeY(m0, acc);
    compute(acc, 0, 1, 2, 3); putS(m0 + 3, 4, R); issue(m0 + 4, R); BARRIER(); storeY(m0 + 1, acc);
    compute(acc, 1, 2, 3, 4); putS(m0 + 4, 0, R); issue(m0 + 5, R); BARRIER(); storeY(m0 + 2, acc);
    compute(acc, 2, 3, 4, 0); putS(m0 + 5, 1, R); issue(m0 + 6, R); BARRIER(); storeY(m0 + 3, acc);
    compute(acc, 3, 4, 0, 1); putS(m0 + 6, 2, R); issue(m0 + 7, R); BARRIER(); storeY(m0 + 4, acc);
  }

  // ---- peeled u=10: m = 51..55, then m=0 wrap with W2'' ----
  float4 RA[2], RB[2];
  compute(acc, 4, 0, 1, 2); putS(53, 3, R); issue(54, R); BARRIER(); storeY(51, acc);
  compute(acc, 0, 1, 2, 3); putS(54, 4, R); issue(55, R); BARRIER(); storeY(52, acc);
  compute(acc, 1, 2, 3, 4); putS(55, 0, R); issue(56, R); BARRIER(); storeY(53, acc); // R <- zeros
  compute(acc, 2, 3, 4, 0); putS(56, 1, R);               BARRIER(); storeY(54, acc);
  compute(acc, 3, 4, 0, 1); issue(0, RA); issue(1, RB);   BARRIER(); storeY(55, acc);
  // wrap: x0 -> slot 1 (slice 56, dead), x1 -> slot 2 (slice 52, dead)
  putS(0, 1, RA); putS(1, 2, RB);
  {
    const unsigned short* ap2 = wp + 16384 + ((16 * iw + lq) << 8) + lg * 8;
    #pragma unroll
    for (int s = 0; s < 8; ++s) afrag[s] = *(const short8_t*)(ap2 + s * 32);
  }
  BARRIER();
  compute(acc, 4, 0, 1, 2);   // taps x54(s4), x55(s0), x0(s1), x1(s2)
  storeY(0, acc);
}

extern "C" void kernel_launch(void* const* d_in, const int* in_sizes, int n_in,
                              void* d_out, int out_size, void* d_ws, size_t ws_size,
                              hipStream_t stream) {
  const float* x  = (const float*)d_in[0];
  const float* W1 = (const float*)d_in[1];
  const float* W2 = (const float*)d_in[2];
  float* out = (float*)d_out;
  unsigned short* wp = (unsigned short*)d_ws;
  prep_weights<<<1, 256, 0, stream>>>(W1, W2, wp);
  conv4tap<<<1024, 512, 0, stream>>>(x, wp, out);
}

// Round 7
// 428.124 us; speedup vs baseline: 1.5263x; 1.0698x over previous
//
#include <hip/hip_runtime.h>

// B=1024, H=56, J=64, N=56, I=64.
// t4[b,i,m,n] = sum_{k,j} x[b, m+k-1, j, n] * W2[i,k,j]   (zero-padded in h)
// y[b,i,m,(n+1)%56] = t4[b,i,m,n]*W1[i,0] + t4[b,i,(m-1)%56,n]*W1[i,1]
//
// Folded 4-tap: y[i,m,c] = sum_{k'} W2'[i,k',j] * x[m-2+k', j, (c-1)%56]
//   W2' = [bW0, aW0+bW1, aW1+bW2, aW2]  (m=1..55); m=0 wrap uses
//   W2'' = [bW0, bW1, aW1, aW2] over x54,x55,x0,x1.  (precomputed in d_ws)
// n-roll via rotated B-rows (col c reads LDS row (c+55)%56).
// LDS 16B-chunk XOR swizzle: phys_chunk = chunk ^ ((row>>2)&7), applied on
// BOTH ds_write (staging) and ds_read (fragments) -> writes 2-way (free),
// reads ~3-way; whole-fragment moves keep MFMA k-order intact.
// Column split 32/24 -> all global stores 32B-sector aligned (no RMW).
// Depth-2 global prefetch (R[0]/R[1], 2-phase gap), 10-substep unroll.

#define HH 56
#define ROWE 328   // ushorts per n-row (656 B, 16B-aligned rows)
#define SLOTE 64

typedef __attribute__((ext_vector_type(8))) short short8_t;
typedef __attribute__((ext_vector_type(4))) float f32x4;

__device__ __forceinline__ unsigned short f2bf(float f) {
  union { float f; unsigned u; } v; v.f = f;
  return (unsigned short)((v.u + 0x7FFFu + ((v.u >> 16) & 1u)) >> 16);
}

#define BARRIER() do {                                   \
    asm volatile("s_waitcnt lgkmcnt(0)" ::: "memory");   \
    __builtin_amdgcn_s_barrier();                        \
  } while (0)

// ---- pre-kernel: merged 4-tap weight sets (bf16) into ws ----
__global__ void prep_weights(const float* __restrict__ W1,
                             const float* __restrict__ W2,
                             unsigned short* __restrict__ wp) {
  const int t = threadIdx.x;            // 256 threads
  const int i = t >> 2;
  const int j0 = (t & 3) * 16;
  const float a = W1[i * 2 + 0], b = W1[i * 2 + 1];
  const float* w = W2 + i * 192;
  unsigned short* p0 = wp + i * 256;            // W2'  (m = 1..55)
  unsigned short* p1 = wp + 16384 + i * 256;    // W2'' (m = 0 wrap)
  for (int j = j0; j < j0 + 16; ++j) {
    const float w0 = w[j], w1 = w[64 + j], w2 = w[128 + j];
    p0[j]       = f2bf(b * w0);
    p0[64 + j]  = f2bf(a * w0 + b * w1);
    p0[128 + j] = f2bf(a * w1 + b * w2);
    p0[192 + j] = f2bf(a * w2);
    p1[j]       = f2bf(b * w0);
    p1[64 + j]  = f2bf(b * w1);
    p1[128 + j] = f2bf(a * w1);
    p1[192 + j] = f2bf(a * w2);
  }
}

__global__ __launch_bounds__(512, 4) void conv4tap(
    const float* __restrict__ x, const unsigned short* __restrict__ wp,
    float* __restrict__ out) {
  __shared__ unsigned short lds[56 * ROWE];   // 36736 B

  const int tid  = threadIdx.x;
  const int wave = tid >> 6;          // 0..7
  const int iw   = wave >> 1;         // i-group: rows 16*iw..16*iw+15
  const int nh   = wave & 1;          // n-part: cols 32*nh .. (0-31 | 32-55)
  const int lane = tid & 63;
  const int lq   = lane & 15;
  const int lg   = lane >> 4;

  const int b = blockIdx.x;
  const float* __restrict__ xb = x + (size_t)b * (HH * 64 * 56);

  // ---- A fragments: W2' (64 x 256 bf16), i = 16*iw + lq ----
  short8_t afrag[8];
  {
    const unsigned short* ap = wp + ((16 * iw + lq) << 8) + lg * 8;
    #pragma unroll
    for (int s = 0; s < 8; ++s) afrag[s] = *(const short8_t*)(ap + s * 32);
  }

  // ---- B read bases (rotated + chunk-swizzled), tile t: c = 32nh+16t+lq ----
  int rbh[2][2];
  #pragma unroll
  for (int t = 0; t < 2; ++t) {
    const int c   = 32 * nh + 16 * t + lq;
    const int row = (c + 55) % 56;
    const int g   = (row >> 2) & 7;
    rbh[t][0] = row * ROWE + ((lg ^ g) << 3);
    rbh[t][1] = row * ROWE + (((lg + 4) ^ g) << 3);
  }

  // ---- output base: i = 16*iw + 4*lg + r, col = 32*nh + 16t + lq ----
  float* const outp = out + ((size_t)b * 64 + 16 * iw + 4 * lg) * (HH * 56)
                      + 32 * nh + lq;

  // ---- staging: 448 active lanes = n-quad(14) x j-pair(32) ----
  const int nq = tid & 15;            // active < 14
  const int jq = tid >> 4;            // 0..31, j rows {2jq, 2jq+1}
  const bool stg = nq < 14;
  const float* const xsrc = xb + (size_t)(2 * jq) * 56 + 4 * nq;
  // swizzled LDS base: rows 4nq+e share g = nq&7; logical chunk = jq>>2
  const int sb = (4 * nq) * ROWE + ((((jq >> 2) ^ (nq & 7)) << 3) + 2 * (jq & 3));

  auto issue = [&](int h, float4* R) {
    if (stg && h <= HH) {
      if (h >= 0 && h < HH) {
        const float* p = xsrc + (size_t)h * (64 * 56);
        R[0] = *(const float4*)(p);
        R[1] = *(const float4*)(p + 56);
      } else {
        float4 z = {0.f, 0.f, 0.f, 0.f};
        R[0] = z; R[1] = z;
      }
    }
  };

  // rows 4nq+e get cols {2jq, 2jq+1} as one packed dword write (swizzled)
  auto putS = [&](int h, int slot, const float4* R) {
    if (stg && h <= HH) {
      unsigned short* base = &lds[sb + slot * SLOTE];
      const unsigned q0 = (unsigned)f2bf(R[0].x) | ((unsigned)f2bf(R[1].x) << 16);
      const unsigned q1 = (unsigned)f2bf(R[0].y) | ((unsigned)f2bf(R[1].y) << 16);
      const unsigned q2 = (unsigned)f2bf(R[0].z) | ((unsigned)f2bf(R[1].z) << 16);
      const unsigned q3 = (unsigned)f2bf(R[0].w) | ((unsigned)f2bf(R[1].w) << 16);
      *(unsigned*)(base)            = q0;
      *(unsigned*)(base + ROWE)     = q1;
      *(unsigned*)(base + 2 * ROWE) = q2;
      *(unsigned*)(base + 3 * ROWE) = q3;
    }
  };

  auto compute = [&](f32x4* acc, int s0, int s1, int s2, int s3) {
    acc[0] = (f32x4){0.f, 0.f, 0.f, 0.f};
    acc[1] = (f32x4){0.f, 0.f, 0.f, 0.f};
    const int sl[4] = {s0, s1, s2, s3};
    #pragma unroll
    for (int s = 0; s < 8; ++s) {
      const int off = sl[s >> 1] * SLOTE;
      const int half = s & 1;
      const short8_t b0 = *(const short8_t*)&lds[rbh[0][half] + off];
      const short8_t b1 = *(const short8_t*)&lds[rbh[1][half] + off];
      acc[0] = __builtin_amdgcn_mfma_f32_16x16x32_bf16(afrag[s], b0, acc[0], 0, 0, 0);
      acc[1] = __builtin_amdgcn_mfma_f32_16x16x32_bf16(afrag[s], b1, acc[1], 0, 0, 0);
    }
  };

  auto storeY = [&](int m, const f32x4* acc) {
    float* pm = outp + m * 56;
    #pragma unroll
    for (int r = 0; r < 4; ++r) {
      pm[(size_t)r * 3136] = acc[0][r];
      if (nh == 0 || lq < 8) pm[(size_t)r * 3136 + 16] = acc[1][r];
    }
  };

  f32x4 acc[2];
  float4 R0[2], R1[2];

  // ---- prologue: stage slices -1,0,1,2 into slots 4,0,1,2; prime depth-2 ----
  issue(-1, R0); putS(-1, 4, R0);
  issue(0, R0);  putS(0, 0, R0);
  issue(1, R0);  putS(1, 1, R0);
  issue(2, R0);  putS(2, 2, R0);
  BARRIER();
  issue(3, R1);             // consumed by putS at m=1 (2-phase pipeline)
  issue(4, R0);             // consumed by putS at m=2

  // phase m: compute taps m-2..m+1; putS slice m+2 (loaded 2 phases ago);
  // issue slice m+4; barrier (lgkm only); store y[m] under next compute.
#define PHASE(MM, S0, S1, S2, S3, SP, RR)                                  \
  do {                                                                     \
    compute(acc, S0, S1, S2, S3);                                          \
    putS((MM) + 2, SP, RR); issue((MM) + 4, RR);                           \
    BARRIER();                                                             \
    storeY((MM), acc);                                                     \
  } while (0)

  // ---- main: m = 1..50, 5 iters x 10 substeps (slots & parity static) ----
  #pragma unroll 1
  for (int u = 0; u < 5; ++u) {
    const int m0 = 10 * u;
    PHASE(m0 + 1, 4, 0, 1, 2, 3, R1);
    PHASE(m0 + 2, 0, 1, 2, 3, 4, R0);
    PHASE(m0 + 3, 1, 2, 3, 4, 0, R1);
    PHASE(m0 + 4, 2, 3, 4, 0, 1, R0);
    PHASE(m0 + 5, 3, 4, 0, 1, 2, R1);
    PHASE(m0 + 6, 4, 0, 1, 2, 3, R0);
    PHASE(m0 + 7, 0, 1, 2, 3, 4, R1);
    PHASE(m0 + 8, 1, 2, 3, 4, 0, R0);
    PHASE(m0 + 9, 2, 3, 4, 0, 1, R1);
    PHASE(m0 + 10, 3, 4, 0, 1, 2, R0);
  }

  // ---- tail m = 51..55 (issue repurposed to preload x0, x1), then wrap ----
  compute(acc, 4, 0, 1, 2); putS(53, 3, R1); issue(55, R1); BARRIER(); storeY(51, acc);
  compute(acc, 0, 1, 2, 3); putS(54, 4, R0); issue(56, R0); BARRIER(); storeY(52, acc);
  compute(acc, 1, 2, 3, 4); putS(55, 0, R1); issue(0, R1);  BARRIER(); storeY(53, acc);
  compute(acc, 2, 3, 4, 0); putS(56, 1, R0); issue(1, R0);  BARRIER(); storeY(54, acc);
  compute(acc, 3, 4, 0, 1);                                 BARRIER(); storeY(55, acc);
  // wrap m=0: slices x54(slot4), x55(slot0) still live; stage x0->2, x1->3
  putS(0, 2, R1); putS(1, 3, R0);
  {
    const unsigned short* ap2 = wp + 16384 + ((16 * iw + lq) << 8) + lg * 8;
    #pragma unroll
    for (int s = 0; s < 8; ++s) afrag[s] = *(const short8_t*)(ap2 + s * 32);
  }
  BARRIER();
  compute(acc, 4, 0, 2, 3);   // taps x54, x55, x0, x1 with W2''
  storeY(0, acc);
#undef PHASE
}

extern "C" void kernel_launch(void* const* d_in, const int* in_sizes, int n_in,
                              void* d_out, int out_size, void* d_ws, size_t ws_size,
                              hipStream_t stream) {
  const float* x  = (const float*)d_in[0];
  const float* W1 = (const float*)d_in[1];
  const float* W2 = (const float*)d_in[2];
  float* out = (float*)d_out;
  unsigned short* wp = (unsigned short*)d_ws;
  prep_weights<<<1, 256, 0, stream>>>(W1, W2, wp);
  conv4tap<<<1024, 512, 0, stream>>>(x, wp, out);
}